// Round 1
// baseline (734.950 us; speedup 1.0000x reference)
//
#include <hip/hip_runtime.h>
#include <cstdint>

typedef __bf16 bf16;
typedef bf16 bf16x2 __attribute__((ext_vector_type(2)));
typedef bf16 bf16x4 __attribute__((ext_vector_type(4)));
typedef bf16 bf16x8 __attribute__((ext_vector_type(8)));
typedef float floatx4 __attribute__((ext_vector_type(4)));

#define SEQ   256
#define DIMM  1024
#define HEADS 16
#define KV_LEN 2125
#define KV_PAD 2176      // per-batch padded token count (17 * 128)
#define KV_BLKS 17
#define VT_NBLK 9        // 256-wide token blocks per batch (covers 2304 >= 2176, tail masked)
#define MS_TOK 2048
#define ATT_SCALE 0.125f
#define TILE_ELEMS (128 * 32)
#define TILE2_ELEMS (256 * 32)

__device__ __forceinline__ void load_lds16(const bf16* g, bf16* l) {
    __builtin_amdgcn_global_load_lds(
        (const __attribute__((address_space(1))) void*)g,
        (__attribute__((address_space(3))) void*)l, 16, 0, 0);
}

// ---------------- fp32 -> bf16 convert (flat) ----------------
__global__ __launch_bounds__(256) void convert_kernel(
        const float* __restrict__ src, bf16* __restrict__ dst, long total) {
    long i4 = ((long)blockIdx.x * 256 + threadIdx.x) * 4;
    if (i4 >= total) return;
    const float4 v = *(const float4*)(src + i4);
    bf16x4 o;
    o[0] = (bf16)v.x; o[1] = (bf16)v.y; o[2] = (bf16)v.z; o[3] = (bf16)v.w;
    *(bf16x4*)(dst + i4) = o;
}

// ------- cond fp32 -> bf16 into per-batch padded layout; pad rows zeroed -------
__global__ __launch_bounds__(256) void convert_cond_kernel(
        const float* __restrict__ src, bf16* __restrict__ dst, long total_dst) {
    long i4 = ((long)blockIdx.x * 256 + threadIdx.x) * 4;
    if (i4 >= total_dst) return;
    long drow = i4 >> 10;
    int b = (int)(drow / KV_PAD);
    int j = (int)(drow - (long)b * KV_PAD);
    bf16x4 o;
    if (j < KV_LEN) {
        long srow = (long)b * KV_LEN + j;
        const float4 v = *(const float4*)(src + (srow << 10) + (i4 & 1023));
        o[0] = (bf16)v.x; o[1] = (bf16)v.y; o[2] = (bf16)v.z; o[3] = (bf16)v.w;
    } else {
        o[0] = o[1] = o[2] = o[3] = (bf16)0.f;
    }
    *(bf16x4*)(dst + i4) = o;
}

// ---------------- W (K x N) -> Wt (N x K) bf16 ----------------
__global__ __launch_bounds__(256) void transpose_bf16_kernel(
        const float* __restrict__ W, bf16* __restrict__ Wt, int N) {
    __shared__ float tile[32][33];
    int n0 = blockIdx.x * 32, k0 = blockIdx.y * 32;
    int r = threadIdx.x >> 5, c = threadIdx.x & 31;
    #pragma unroll
    for (int i = 0; i < 4; ++i)
        tile[r + i * 8][c] = W[(size_t)(k0 + r + i * 8) * N + n0 + c];
    __syncthreads();
    #pragma unroll
    for (int i = 0; i < 4; ++i)
        Wt[(size_t)(n0 + r + i * 8) * N + k0 + c] = (bf16)tile[c][r + i * 8];
}

// ------- precompute rotary cos/sin tables + per-(mem,head) bias table -------
__global__ __launch_bounds__(256) void rot_tables_kernel(
        const float* __restrict__ freqs, const float* __restrict__ rel_table,
        const int* __restrict__ mem_idxs, const int* __restrict__ cur,
        float* __restrict__ ckT, float* __restrict__ skT,
        float* __restrict__ cqT, float* __restrict__ sqT,
        float* __restrict__ biasK) {
    int t = blockIdx.x * 256 + threadIdx.x;
    const int cp = *cur; const int inner = cp & 15;
    const int rs = inner & 3, cs = inner >> 2, ts = cp >> 4;
    if (t < MS_TOK * 64) {
        int j = t >> 6, d = t & 63;
        int mi = mem_idxs[j >> 8];
        int rt = mi & 3, ct = (mi >> 2) & 3;
        int pidx = j & 255;
        int fr = rt * 16 + (pidx >> 4), fc = ct * 16 + (pidx & 15);
        float f = freqs[(size_t)(fr * 64 + fc) * 64 + d];
        ckT[t] = __cosf(f); skT[t] = __sinf(f);
    } else if (t < MS_TOK * 64 + SEQ * 64) {
        int t2 = t - MS_TOK * 64;
        int s = t2 >> 6, d = t2 & 63;
        int fr = rs * 16 + (s >> 4), fc = cs * 16 + (s & 15);
        float f = freqs[(size_t)(fr * 64 + fc) * 64 + d];
        cqT[t2] = __cosf(f); sqT[t2] = __sinf(f);
    } else if (t < MS_TOK * 64 + SEQ * 64 + 128) {
        int t3 = t - (MS_TOK * 64 + SEQ * 64);
        int m = t3 >> 4, h = t3 & 15;
        int mi = mem_idxs[m];
        int rt = mi & 3, ct = (mi >> 2) & 3, tt = mi >> 4;
        int rel = (rt - rs + 4) * 9 + (ct - cs + 4) + (tt - ts + 4) * 81;
        biasK[t3] = rel_table[rel * HEADS + h];
    }
}

// ===== 128x128 pipelined GEMM core (kept for Q/O GEMMs): double-buffered LDS,
// one barrier per K-iteration. =====
__device__ __forceinline__ void gemm_loop_db(
        const bf16* __restrict__ Ag, const bf16* __restrict__ Bg, int K,
        bf16* __restrict__ As, bf16* __restrict__ Bs,
        floatx4 (&acc)[4][4]) {
    const int tid  = threadIdx.x;
    const int wave = tid >> 6, lane = tid & 63;
    const int quad = lane >> 4, l16 = lane & 15;
    const int wm = wave >> 1, wn = wave & 1;
    #pragma unroll
    for (int i = 0; i < 2; ++i) {
        int c = i * 256 + wave * 64 + lane;
        int r = c >> 2, c8 = (c & 3) * 8;
        load_lds16(Ag + (long)r * K + c8, As + (i * 256 + wave * 64) * 8);
        load_lds16(Bg + (long)r * K + c8, Bs + (i * 256 + wave * 64) * 8);
    }
    for (int k0 = 0; k0 < K; k0 += 32) {
        const int cur = (k0 >> 5) & 1;
        bf16* Asc = As + cur * TILE_ELEMS;
        bf16* Bsc = Bs + cur * TILE_ELEMS;
        __syncthreads();                       // drains DMA of tile k0; readers of prev buffer done
        if (k0 + 32 < K) {
            bf16* Asn = As + (cur ^ 1) * TILE_ELEMS;
            bf16* Bsn = Bs + (cur ^ 1) * TILE_ELEMS;
            #pragma unroll
            for (int i = 0; i < 2; ++i) {
                int c = i * 256 + wave * 64 + lane;
                int r = c >> 2, c8 = (c & 3) * 8;
                load_lds16(Ag + (long)r * K + k0 + 32 + c8, Asn + (i * 256 + wave * 64) * 8);
                load_lds16(Bg + (long)r * K + k0 + 32 + c8, Bsn + (i * 256 + wave * 64) * 8);
            }
        }
        bf16x8 af[4], bfr[4];
        #pragma unroll
        for (int mt = 0; mt < 4; ++mt)
            af[mt] = *(const bf16x8*)(Asc + (wm * 64 + mt * 16 + l16) * 32 + quad * 8);
        #pragma unroll
        for (int nt = 0; nt < 4; ++nt)
            bfr[nt] = *(const bf16x8*)(Bsc + (wn * 64 + nt * 16 + l16) * 32 + quad * 8);
        #pragma unroll
        for (int mt = 0; mt < 4; ++mt)
            #pragma unroll
            for (int nt = 0; nt < 4; ++nt)
                acc[mt][nt] = __builtin_amdgcn_mfma_f32_16x16x32_bf16(af[mt], bfr[nt], acc[mt][nt], 0, 0, 0);
    }
}

// ===== 256x256 GEMM core: 8 waves (2M x 4N), BK=32, same 2-phase sync
// structure as gemm_loop_db. 4x arithmetic intensity per staged byte ->
// the per-iteration vmcnt(0) drain is covered by ~2x more MFMA cycles/SIMD. =====
__device__ __forceinline__ void gemm_loop_256(
        const bf16* __restrict__ Ag, const bf16* __restrict__ Bg, int K,
        bf16* __restrict__ As, bf16* __restrict__ Bs,
        floatx4 (&acc)[8][4]) {
    const int tid  = threadIdx.x;
    const int wave = tid >> 6, lane = tid & 63;
    const int quad = lane >> 4, l16 = lane & 15;
    const int wm = wave >> 2, wn = wave & 3;
    #pragma unroll
    for (int i = 0; i < 2; ++i) {
        int c = i * 512 + tid;
        int r = c >> 2, c8 = (c & 3) * 8;
        load_lds16(Ag + (long)r * K + c8, As + (i * 512 + wave * 64) * 8);
        load_lds16(Bg + (long)r * K + c8, Bs + (i * 512 + wave * 64) * 8);
    }
    for (int k0 = 0; k0 < K; k0 += 32) {
        const int cur = (k0 >> 5) & 1;
        bf16* Asc = As + cur * TILE2_ELEMS;
        bf16* Bsc = Bs + cur * TILE2_ELEMS;
        __syncthreads();                       // drains DMA of tile k0
        if (k0 + 32 < K) {
            bf16* Asn = As + (cur ^ 1) * TILE2_ELEMS;
            bf16* Bsn = Bs + (cur ^ 1) * TILE2_ELEMS;
            #pragma unroll
            for (int i = 0; i < 2; ++i) {
                int c = i * 512 + tid;
                int r = c >> 2, c8 = (c & 3) * 8;
                load_lds16(Ag + (long)r * K + k0 + 32 + c8, Asn + (i * 512 + wave * 64) * 8);
                load_lds16(Bg + (long)r * K + k0 + 32 + c8, Bsn + (i * 512 + wave * 64) * 8);
            }
        }
        bf16x8 af[8], bfr[4];
        #pragma unroll
        for (int mt = 0; mt < 8; ++mt)
            af[mt] = *(const bf16x8*)(Asc + (wm * 128 + mt * 16 + l16) * 32 + quad * 8);
        #pragma unroll
        for (int nt = 0; nt < 4; ++nt)
            bfr[nt] = *(const bf16x8*)(Bsc + (wn * 64 + nt * 16 + l16) * 32 + quad * 8);
        #pragma unroll
        for (int mt = 0; mt < 8; ++mt)
            #pragma unroll
            for (int nt = 0; nt < 4; ++nt)
                acc[mt][nt] = __builtin_amdgcn_mfma_f32_16x16x32_bf16(af[mt], bfr[nt], acc[mt][nt], 0, 0, 0);
    }
}

// ---------------- O projection: fp32 out + bias (128^2) ----------------
__global__ __launch_bounds__(256) void gemm_o_kernel(
        const bf16* __restrict__ A, const bf16* __restrict__ Bt,
        float* __restrict__ Cout, const float* __restrict__ bias, int N) {
    __shared__ bf16 As[2 * TILE_ELEMS];
    __shared__ bf16 Bs[2 * TILE_ELEMS];
    const int tid  = threadIdx.x;
    const int wave = tid >> 6, lane = tid & 63;
    const int quad = lane >> 4, l16 = lane & 15;
    const int wm = wave >> 1, wn = wave & 1;
    const long row0 = (long)blockIdx.x * 128, col0 = (long)blockIdx.y * 128;
    floatx4 acc[4][4] = {};
    gemm_loop_db(A + row0 * DIMM, Bt + col0 * DIMM, DIMM, As, Bs, acc);
    #pragma unroll
    for (int mt = 0; mt < 4; ++mt) {
        #pragma unroll
        for (int nt = 0; nt < 4; ++nt) {
            long r = row0 + wm * 64 + mt * 16 + quad * 4;
            long ccol = col0 + wn * 64 + nt * 16 + l16;
            float bv = bias[ccol];
            #pragma unroll
            for (int i = 0; i < 4; ++i)
                Cout[(r + i) * (long)N + ccol] = acc[mt][nt][i] + bv;
        }
    }
}

// ---------------- Q GEMM with fused table-based rotary epilogue (128^2) ----------------
__global__ __launch_bounds__(256) void gemm_q_rot_kernel(
        const bf16* __restrict__ A, const bf16* __restrict__ Bt,
        bf16* __restrict__ Qout, const float* __restrict__ cqT,
        const float* __restrict__ sqT) {
    __shared__ bf16 As[2 * TILE_ELEMS];
    __shared__ bf16 Bs[2 * TILE_ELEMS];
    const int tid  = threadIdx.x;
    const int wave = tid >> 6, lane = tid & 63;
    const int quad = lane >> 4, l16 = lane & 15;
    const int wm = wave >> 1, wn = wave & 1;
    const long row0 = (long)blockIdx.x * 128, col0 = (long)blockIdx.y * 128;
    floatx4 acc[4][4] = {};
    gemm_loop_db(A + row0 * DIMM, Bt + col0 * DIMM, DIMM, As, Bs, acc);
    #pragma unroll
    for (int mt = 0; mt < 4; ++mt) {
        #pragma unroll
        for (int nt = 0; nt < 4; ++nt) {
            long rr = row0 + wm * 64 + mt * 16 + quad * 4;
            int ccol = (int)col0 + wn * 64 + nt * 16 + l16;
            int d = ccol & 63;
            #pragma unroll
            for (int i = 0; i < 4; ++i) {
                long r = rr + i; int s = (int)(r & 255);
                float c_ = cqT[s * 64 + d], s_ = sqT[s * 64 + d];
                float q = acc[mt][nt][i];
                float pn = __shfl_xor(q, 1);
                float outv = (d & 1) ? (q * c_ + pn * s_) : (q * c_ - pn * s_);
                Qout[r * DIMM + ccol] = (bf16)outv;
            }
        }
    }
}

// -------- K GEMM (256^2, 8 waves) with fused bias + rotary epilogue --------
__global__ __launch_bounds__(512, 2) void gemm_k_kernel(
        const bf16* __restrict__ A, const bf16* __restrict__ Btk,
        bf16* __restrict__ Kout, const float* __restrict__ ckT,
        const float* __restrict__ skT, const float* __restrict__ biasK) {
    __shared__ bf16 As[2 * TILE2_ELEMS];
    __shared__ bf16 Bs[2 * TILE2_ELEMS];
    const int tid  = threadIdx.x;
    const int wave = tid >> 6, lane = tid & 63;
    const int quad = lane >> 4, l16 = lane & 15;
    const int wm = wave >> 2, wn = wave & 3;
    const long row0 = (long)blockIdx.x * 256, col0 = (long)blockIdx.y * 256;
    floatx4 acc[8][4] = {};
    gemm_loop_256(A + row0 * DIMM, Btk + col0 * DIMM, DIMM, As, Bs, acc);
    // 256-row tiles straddle batch boundaries (2176 % 256 != 0): per-row batch index.
    // 4-row fragments never straddle (boundaries are multiples of 128).
    #pragma unroll
    for (int mt = 0; mt < 8; ++mt) {
        #pragma unroll
        for (int nt = 0; nt < 4; ++nt) {
            int rr = (int)row0 + wm * 128 + mt * 16 + quad * 4;
            int ccol = (int)col0 + wn * 64 + nt * 16 + l16;
            int h = ccol >> 6, d = ccol & 63;
            int bidx = rr / KV_PAD;                 // const divisor -> magic mul
            int jbase = rr - bidx * KV_PAD;
            #pragma unroll
            for (int i = 0; i < 4; ++i) {
                int j = jbase + i;
                float kb = acc[mt][nt][i];
                float c_ = 1.f, s_ = 0.f;
                if (j < MS_TOK) {
                    kb += biasK[((j >> 8) << 4) + h];
                    c_ = ckT[j * 64 + d]; s_ = skT[j * 64 + d];
                }
                float pn = __shfl_xor(kb, 1);
                float outv = (d & 1) ? (kb * c_ + pn * s_) : (kb * c_ - pn * s_);
                Kout[(long)(rr + i) * DIMM + ccol] = (bf16)outv;
            }
        }
    }
}

// -------- V^T GEMM (256^2, 8 waves): VT[(b*1024+f), t]; columns are tokens.
// Token dim tiled 9 x 256 = 2304 > 2176: tail fragments write-masked; the
// overread B rows only pollute unwritten output columns (col j depends only
// on B row j) and stay inside the workspace (finite bf16). --------
__global__ __launch_bounds__(512, 2) void gemm_vt_kernel(
        const bf16* __restrict__ Wvt, const bf16* __restrict__ condb,
        bf16* __restrict__ VT) {
    __shared__ bf16 As[2 * TILE2_ELEMS];
    __shared__ bf16 Bs[2 * TILE2_ELEMS];
    const int tid  = threadIdx.x;
    const int wave = tid >> 6, lane = tid & 63;
    const int quad = lane >> 4, l16 = lane & 15;
    const int wm = wave >> 2, wn = wave & 3;
    const int b  = blockIdx.y / VT_NBLK, tb = blockIdx.y % VT_NBLK;
    const long row0 = (long)blockIdx.x * 256;   // feature
    const long col0 = (long)tb * 256;           // token within batch
    const bf16* Bt = condb + (size_t)b * KV_PAD * DIMM;
    floatx4 acc[8][4] = {};
    gemm_loop_256(Wvt + row0 * DIMM, Bt + col0 * DIMM, DIMM, As, Bs, acc);
    #pragma unroll
    for (int mt = 0; mt < 8; ++mt) {
        #pragma unroll
        for (int nt = 0; nt < 4; ++nt) {
            int tfrag = (int)col0 + wn * 64 + nt * 16;
            if (tfrag < KV_PAD) {
                long f0 = row0 + wm * 128 + mt * 16 + quad * 4;
                long t0 = tfrag + l16;
                #pragma unroll
                for (int i = 0; i < 4; ++i)
                    VT[((size_t)b * DIMM + f0 + i) * KV_PAD + t0] = (bf16)acc[mt][nt][i];
            }
        }
    }
}

// ---------------- flash attention v4: register-prefetched staging ----------------
__global__ __launch_bounds__(256, 3) void attn_kernel(
        const bf16* __restrict__ Qb, const bf16* __restrict__ Kb,
        const bf16* __restrict__ VT, bf16* __restrict__ Ob) {
    const int bh = blockIdx.x & 255, qt = blockIdx.x >> 8;
    const int b = bh >> 4, h = bh & 15;
    const int tid = threadIdx.x, wave = tid >> 6, lane = tid & 63;
    const int quad = lane >> 4, l16 = lane & 15;
    __shared__ bf16 Ks[128 * 72];
    __shared__ bf16 Vt[64 * 144];
    __shared__ bf16 Ps[4][16 * 72];

    const int qrow0 = b * SEQ + qt * 64 + wave * 16;
    const bf16* qp = Qb + (size_t)(qrow0 + l16) * DIMM + h * 64 + quad * 8;
    bf16x8 qf0 = *(const bf16x8*)(qp);
    bf16x8 qf1 = *(const bf16x8*)(qp + 32);

    floatx4 oacc[4] = {};
    floatx4 lacc = {};
    bf16x8 ones;
    #pragma unroll
    for (int t = 0; t < 8; ++t) ones[t] = (bf16)1.0f;

    const size_t kbase = ((size_t)b * KV_PAD) * DIMM + h * 64;
    const size_t vbase = ((size_t)(bh * 64)) * KV_PAD;

    const int kchunk = tid & 1;
    const int gl = tid >> 1;
    const int g  = ((gl & 31) << 2) | (gl >> 5);
    const int gg = g & 63;
    const int dstrow = (g >> 6) * 64 + ((gg & 3) << 4) + (gg >> 2);
    const int vd = tid >> 2, vseg = tid & 3;

    bf16x8 kr[4], vr[4];
    // prefetch tile 0
    {
        int jr = g; if (jr > KV_LEN - 1) jr = KV_LEN - 1;
        const bf16* gp = Kb + kbase + (size_t)jr * DIMM + kchunk * 32;
        kr[0] = *(const bf16x8*)(gp);      kr[1] = *(const bf16x8*)(gp + 8);
        kr[2] = *(const bf16x8*)(gp + 16); kr[3] = *(const bf16x8*)(gp + 24);
        const bf16* vp = VT + vbase + (size_t)vd * KV_PAD + vseg * 32;
        vr[0] = *(const bf16x8*)(vp);      vr[1] = *(const bf16x8*)(vp + 8);
        vr[2] = *(const bf16x8*)(vp + 16); vr[3] = *(const bf16x8*)(vp + 24);
    }

    for (int j0 = 0; j0 < KV_LEN; j0 += 128) {
        __syncthreads();           // previous iteration's LDS readers done
        {
            bf16* dp = Ks + dstrow * 72 + kchunk * 32;
            *(bf16x8*)(dp)      = kr[0]; *(bf16x8*)(dp + 8)  = kr[1];
            *(bf16x8*)(dp + 16) = kr[2]; *(bf16x8*)(dp + 24) = kr[3];
            bf16* dv = Vt + vd * 144 + vseg * 32;
            *(bf16x8*)(dv)      = vr[0]; *(bf16x8*)(dv + 8)  = vr[1];
            *(bf16x8*)(dv + 16) = vr[2]; *(bf16x8*)(dv + 24) = vr[3];
        }
        __syncthreads();           // LDS tile ready
        if (j0 + 128 < KV_LEN) {   // prefetch next tile; completes during compute
            int jr = j0 + 128 + g; if (jr > KV_LEN - 1) jr = KV_LEN - 1;
            const bf16* gp = Kb + kbase + (size_t)jr * DIMM + kchunk * 32;
            kr[0] = *(const bf16x8*)(gp);      kr[1] = *(const bf16x8*)(gp + 8);
            kr[2] = *(const bf16x8*)(gp + 16); kr[3] = *(const bf16x8*)(gp + 24);
            const bf16* vp = VT + vbase + (size_t)vd * KV_PAD + j0 + 128 + vseg * 32;
            vr[0] = *(const bf16x8*)(vp);      vr[1] = *(const bf16x8*)(vp + 8);
            vr[2] = *(const bf16x8*)(vp + 16); vr[3] = *(const bf16x8*)(vp + 24);
        }
        #pragma unroll
        for (int c = 0; c < 2; ++c) {
            floatx4 s[4] = {};
            #pragma unroll
            for (int jt = 0; jt < 4; ++jt) {
                const bf16* kp = Ks + (c * 64 + jt * 16 + l16) * 72 + quad * 8;
                bf16x8 kb0 = *(const bf16x8*)(kp);
                bf16x8 kb1 = *(const bf16x8*)(kp + 32);
                s[jt] = __builtin_amdgcn_mfma_f32_16x16x32_bf16(qf0, kb0, s[jt], 0, 0, 0);
                s[jt] = __builtin_amdgcn_mfma_f32_16x16x32_bf16(qf1, kb1, s[jt], 0, 0, 0);
            }
            const int colbase = j0 + c * 64 + 4 * l16;
            #pragma unroll
            for (int r = 0; r < 4; ++r) {
                bf16x4 pk;
                #pragma unroll
                for (int jt = 0; jt < 4; ++jt) {
                    bool ok = (colbase + jt) < KV_LEN;
                    float p = ok ? __expf(s[jt][r] * ATT_SCALE) : 0.f;
                    pk[jt] = (bf16)p;
                }
                *(bf16x4*)(&Ps[wave][(quad * 4 + r) * 72 + l16 * 4]) = pk;
            }
            #pragma unroll
            for (int kf = 0; kf < 2; ++kf) {
                bf16x8 pa = *(const bf16x8*)(&Ps[wave][l16 * 72 + kf * 32 + quad * 8]);
                lacc = __builtin_amdgcn_mfma_f32_16x16x32_bf16(pa, ones, lacc, 0, 0, 0);
                #pragma unroll
                for (int dt = 0; dt < 4; ++dt) {
                    bf16x8 vb = *(const bf16x8*)(Vt + (dt * 16 + l16) * 144 + c * 64 + kf * 32 + quad * 8);
                    oacc[dt] = __builtin_amdgcn_mfma_f32_16x16x32_bf16(pa, vb, oacc[dt], 0, 0, 0);
                }
            }
        }
    }
    #pragma unroll
    for (int r = 0; r < 4; ++r) {
        float inv = 1.f / lacc[r];
        size_t orow = (size_t)(qrow0 + quad * 4 + r) * DIMM + h * 64;
        #pragma unroll
        for (int dt = 0; dt < 4; ++dt)
            Ob[orow + dt * 16 + l16] = (bf16)(oacc[dt][r] * inv);
    }
}

extern "C" void kernel_launch(void* const* d_in, const int* in_sizes, int n_in,
                              void* d_out, int out_size, void* d_ws, size_t ws_size,
                              hipStream_t stream) {
    const float* x     = (const float*)d_in[0];
    const float* cond  = (const float*)d_in[1];
    const float* freqs = (const float*)d_in[2];
    const float* Wq    = (const float*)d_in[3];
    const float* Wk    = (const float*)d_in[4];
    const float* Wv    = (const float*)d_in[5];
    const float* rel   = (const float*)d_in[6];
    const float* Wo    = (const float*)d_in[7];
    const float* bo    = (const float*)d_in[8];
    const int* mem_idxs = (const int*)d_in[9];
    const int* cur      = (const int*)d_in[10];
    float* out = (float*)d_out;

    const int B   = 16;
    const int Mq  = B * SEQ;                 // 4096
    const int Mkv_pad = B * KV_PAD;          // 34816 = 136 * 256

    char* ws = (char*)d_ws;
    size_t off = 0;
    auto alloc = [&](size_t bytes) { void* pp = ws + off; off = (off + bytes + 255) & ~(size_t)255; return pp; };
    bf16* xb    = (bf16*)alloc((size_t)Mq * DIMM * 2);
    bf16* condb = (bf16*)alloc((size_t)Mkv_pad * DIMM * 2);
    bf16* Wqt   = (bf16*)alloc((size_t)DIMM * DIMM * 2);
    bf16* Wkt   = (bf16*)alloc((size_t)DIMM * DIMM * 2);
    bf16* Wvt   = (bf16*)alloc((size_t)DIMM * DIMM * 2);
    bf16* Wot   = (bf16*)alloc((size_t)DIMM * DIMM * 2);
    bf16* Qb    = (bf16*)alloc((size_t)Mq * DIMM * 2);
    bf16* Kb    = (bf16*)alloc((size_t)Mkv_pad * DIMM * 2);
    bf16* VTb   = (bf16*)alloc((size_t)B * DIMM * KV_PAD * 2);
    bf16* Ab    = (bf16*)alloc((size_t)Mq * DIMM * 2);
    float* ckT  = (float*)alloc((size_t)MS_TOK * 64 * 4);
    float* skT  = (float*)alloc((size_t)MS_TOK * 64 * 4);
    float* cqT  = (float*)alloc((size_t)SEQ * 64 * 4);
    float* sqT  = (float*)alloc((size_t)SEQ * 64 * 4);
    float* biasK = (float*)alloc(128 * 4);

    long xtot = (long)Mq * DIMM;
    convert_kernel<<<(int)((xtot / 4 + 255) / 256), 256, 0, stream>>>(x, xb, xtot);
    long ctot = (long)Mkv_pad * DIMM;
    convert_cond_kernel<<<(int)((ctot / 4 + 255) / 256), 256, 0, stream>>>(cond, condb, ctot);
    dim3 tg(32, 32);
    transpose_bf16_kernel<<<tg, 256, 0, stream>>>(Wq, Wqt, DIMM);
    transpose_bf16_kernel<<<tg, 256, 0, stream>>>(Wk, Wkt, DIMM);
    transpose_bf16_kernel<<<tg, 256, 0, stream>>>(Wv, Wvt, DIMM);
    transpose_bf16_kernel<<<tg, 256, 0, stream>>>(Wo, Wot, DIMM);

    int ttot = MS_TOK * 64 + SEQ * 64 + 128;
    rot_tables_kernel<<<(ttot + 255) / 256, 256, 0, stream>>>(
        freqs, rel, mem_idxs, cur, ckT, skT, cqT, sqT, biasK);

    gemm_q_rot_kernel<<<dim3(Mq / 128, 8), 256, 0, stream>>>(xb, Wqt, Qb, cqT, sqT);
    gemm_k_kernel<<<dim3(Mkv_pad / 256, DIMM / 256), 512, 0, stream>>>(condb, Wkt, Kb, ckT, skT, biasK);
    gemm_vt_kernel<<<dim3(DIMM / 256, B * VT_NBLK), 512, 0, stream>>>(Wvt, condb, VTb);

    attn_kernel<<<4 * B * HEADS, 256, 0, stream>>>(Qb, Kb, VTb, Ab);

    gemm_o_kernel<<<dim3(Mq / 128, 8), 256, 0, stream>>>(Ab, Wot, out, bo, DIMM);
}

// Round 2
// 590.349 us; speedup vs baseline: 1.2449x; 1.2449x over previous
//
#include <hip/hip_runtime.h>
#include <cstdint>

typedef __bf16 bf16;
typedef bf16 bf16x2 __attribute__((ext_vector_type(2)));
typedef bf16 bf16x4 __attribute__((ext_vector_type(4)));
typedef bf16 bf16x8 __attribute__((ext_vector_type(8)));
typedef float floatx4 __attribute__((ext_vector_type(4)));

#define SEQ   256
#define DIMM  1024
#define HEADS 16
#define KV_LEN 2125
#define KV_PAD 2176      // per-batch padded token count (17 * 128)
#define KV_BLKS 17
#define MS_TOK 2048
#define ATT_SCALE 0.125f
#define TILE_ELEMS (128 * 32)

__device__ __forceinline__ void load_lds16(const bf16* g, bf16* l) {
    __builtin_amdgcn_global_load_lds(
        (const __attribute__((address_space(1))) void*)g,
        (__attribute__((address_space(3))) void*)l, 16, 0, 0);
}

// ---------------- fp32 -> bf16 convert (flat) ----------------
__global__ __launch_bounds__(256) void convert_kernel(
        const float* __restrict__ src, bf16* __restrict__ dst, long total) {
    long i4 = ((long)blockIdx.x * 256 + threadIdx.x) * 4;
    if (i4 >= total) return;
    const float4 v = *(const float4*)(src + i4);
    bf16x4 o;
    o[0] = (bf16)v.x; o[1] = (bf16)v.y; o[2] = (bf16)v.z; o[3] = (bf16)v.w;
    *(bf16x4*)(dst + i4) = o;
}

// ------- cond fp32 -> bf16 into per-batch padded layout; pad rows zeroed -------
__global__ __launch_bounds__(256) void convert_cond_kernel(
        const float* __restrict__ src, bf16* __restrict__ dst, long total_dst) {
    long i4 = ((long)blockIdx.x * 256 + threadIdx.x) * 4;
    if (i4 >= total_dst) return;
    long drow = i4 >> 10;
    int b = (int)(drow / KV_PAD);
    int j = (int)(drow - (long)b * KV_PAD);
    bf16x4 o;
    if (j < KV_LEN) {
        long srow = (long)b * KV_LEN + j;
        const float4 v = *(const float4*)(src + (srow << 10) + (i4 & 1023));
        o[0] = (bf16)v.x; o[1] = (bf16)v.y; o[2] = (bf16)v.z; o[3] = (bf16)v.w;
    } else {
        o[0] = o[1] = o[2] = o[3] = (bf16)0.f;
    }
    *(bf16x4*)(dst + i4) = o;
}

// ---------------- W (K x N) -> Wt (N x K) bf16 ----------------
__global__ __launch_bounds__(256) void transpose_bf16_kernel(
        const float* __restrict__ W, bf16* __restrict__ Wt, int N) {
    __shared__ float tile[32][33];
    int n0 = blockIdx.x * 32, k0 = blockIdx.y * 32;
    int r = threadIdx.x >> 5, c = threadIdx.x & 31;
    #pragma unroll
    for (int i = 0; i < 4; ++i)
        tile[r + i * 8][c] = W[(size_t)(k0 + r + i * 8) * N + n0 + c];
    __syncthreads();
    #pragma unroll
    for (int i = 0; i < 4; ++i)
        Wt[(size_t)(n0 + r + i * 8) * N + k0 + c] = (bf16)tile[c][r + i * 8];
}

// ------- precompute rotary cos/sin tables + per-(mem,head) bias table -------
__global__ __launch_bounds__(256) void rot_tables_kernel(
        const float* __restrict__ freqs, const float* __restrict__ rel_table,
        const int* __restrict__ mem_idxs, const int* __restrict__ cur,
        float* __restrict__ ckT, float* __restrict__ skT,
        float* __restrict__ cqT, float* __restrict__ sqT,
        float* __restrict__ biasK) {
    int t = blockIdx.x * 256 + threadIdx.x;
    const int cp = *cur; const int inner = cp & 15;
    const int rs = inner & 3, cs = inner >> 2, ts = cp >> 4;
    if (t < MS_TOK * 64) {
        int j = t >> 6, d = t & 63;
        int mi = mem_idxs[j >> 8];
        int rt = mi & 3, ct = (mi >> 2) & 3;
        int pidx = j & 255;
        int fr = rt * 16 + (pidx >> 4), fc = ct * 16 + (pidx & 15);
        float f = freqs[(size_t)(fr * 64 + fc) * 64 + d];
        ckT[t] = __cosf(f); skT[t] = __sinf(f);
    } else if (t < MS_TOK * 64 + SEQ * 64) {
        int t2 = t - MS_TOK * 64;
        int s = t2 >> 6, d = t2 & 63;
        int fr = rs * 16 + (s >> 4), fc = cs * 16 + (s & 15);
        float f = freqs[(size_t)(fr * 64 + fc) * 64 + d];
        cqT[t2] = __cosf(f); sqT[t2] = __sinf(f);
    } else if (t < MS_TOK * 64 + SEQ * 64 + 128) {
        int t3 = t - (MS_TOK * 64 + SEQ * 64);
        int m = t3 >> 4, h = t3 & 15;
        int mi = mem_idxs[m];
        int rt = mi & 3, ct = (mi >> 2) & 3, tt = mi >> 4;
        int rel = (rt - rs + 4) * 9 + (ct - cs + 4) + (tt - ts + 4) * 81;
        biasK[t3] = rel_table[rel * HEADS + h];
    }
}

// ===== pipelined GEMM core: double-buffered LDS, ONE barrier per K-iteration.
// DMA for tile k+1 is issued right after the barrier, so its vmcnt(0) drain
// (at the next barrier) lands after a full MFMA phase instead of before it. =====
__device__ __forceinline__ void gemm_loop_db(
        const bf16* __restrict__ Ag, const bf16* __restrict__ Bg, int K,
        bf16* __restrict__ As, bf16* __restrict__ Bs,
        floatx4 (&acc)[4][4]) {
    const int tid  = threadIdx.x;
    const int wave = tid >> 6, lane = tid & 63;
    const int quad = lane >> 4, l16 = lane & 15;
    const int wm = wave >> 1, wn = wave & 1;
    #pragma unroll
    for (int i = 0; i < 2; ++i) {
        int c = i * 256 + wave * 64 + lane;
        int r = c >> 2, c8 = (c & 3) * 8;
        load_lds16(Ag + (long)r * K + c8, As + (i * 256 + wave * 64) * 8);
        load_lds16(Bg + (long)r * K + c8, Bs + (i * 256 + wave * 64) * 8);
    }
    for (int k0 = 0; k0 < K; k0 += 32) {
        const int cur = (k0 >> 5) & 1;
        bf16* Asc = As + cur * TILE_ELEMS;
        bf16* Bsc = Bs + cur * TILE_ELEMS;
        __syncthreads();                       // drains DMA of tile k0; readers of prev buffer done
        if (k0 + 32 < K) {
            bf16* Asn = As + (cur ^ 1) * TILE_ELEMS;
            bf16* Bsn = Bs + (cur ^ 1) * TILE_ELEMS;
            #pragma unroll
            for (int i = 0; i < 2; ++i) {
                int c = i * 256 + wave * 64 + lane;
                int r = c >> 2, c8 = (c & 3) * 8;
                load_lds16(Ag + (long)r * K + k0 + 32 + c8, Asn + (i * 256 + wave * 64) * 8);
                load_lds16(Bg + (long)r * K + k0 + 32 + c8, Bsn + (i * 256 + wave * 64) * 8);
            }
        }
        bf16x8 af[4], bfr[4];
        #pragma unroll
        for (int mt = 0; mt < 4; ++mt)
            af[mt] = *(const bf16x8*)(Asc + (wm * 64 + mt * 16 + l16) * 32 + quad * 8);
        #pragma unroll
        for (int nt = 0; nt < 4; ++nt)
            bfr[nt] = *(const bf16x8*)(Bsc + (wn * 64 + nt * 16 + l16) * 32 + quad * 8);
        #pragma unroll
        for (int mt = 0; mt < 4; ++mt)
            #pragma unroll
            for (int nt = 0; nt < 4; ++nt)
                acc[mt][nt] = __builtin_amdgcn_mfma_f32_16x16x32_bf16(af[mt], bfr[nt], acc[mt][nt], 0, 0, 0);
    }
}

// ---------------- O projection: fp32 out + bias ----------------
// XCD-swizzled 1-D grid (256 = 8 xcd * 4 row-panels * 8 col-blocks):
// all 8 col-blocks of a row-panel run consecutively on one XCD -> A panel L2-hits.
__global__ __launch_bounds__(256) void gemm_o_kernel(
        const bf16* __restrict__ A, const bf16* __restrict__ Bt,
        float* __restrict__ Cout, const float* __restrict__ bias, int N) {
    __shared__ bf16 As[2 * TILE_ELEMS];
    __shared__ bf16 Bs[2 * TILE_ELEMS];
    const int tid  = threadIdx.x;
    const int wave = tid >> 6, lane = tid & 63;
    const int quad = lane >> 4, l16 = lane & 15;
    const int wm = wave >> 1, wn = wave & 1;
    const int L = blockIdx.x, xcd = L & 7, ii = L >> 3;
    const long row0 = (long)(xcd * 4 + (ii >> 3)) * 128;
    const long col0 = (long)(ii & 7) * 128;
    floatx4 acc[4][4] = {};
    gemm_loop_db(A + row0 * DIMM, Bt + col0 * DIMM, DIMM, As, Bs, acc);
    #pragma unroll
    for (int mt = 0; mt < 4; ++mt) {
        #pragma unroll
        for (int nt = 0; nt < 4; ++nt) {
            long r = row0 + wm * 64 + mt * 16 + quad * 4;
            long ccol = col0 + wn * 64 + nt * 16 + l16;
            float bv = bias[ccol];
            #pragma unroll
            for (int i = 0; i < 4; ++i)
                Cout[(r + i) * (long)N + ccol] = acc[mt][nt][i] + bv;
        }
    }
}

// ---------------- Q GEMM with fused table-based rotary epilogue ----------------
__global__ __launch_bounds__(256) void gemm_q_rot_kernel(
        const bf16* __restrict__ A, const bf16* __restrict__ Bt,
        bf16* __restrict__ Qout, const float* __restrict__ cqT,
        const float* __restrict__ sqT) {
    __shared__ bf16 As[2 * TILE_ELEMS];
    __shared__ bf16 Bs[2 * TILE_ELEMS];
    const int tid  = threadIdx.x;
    const int wave = tid >> 6, lane = tid & 63;
    const int quad = lane >> 4, l16 = lane & 15;
    const int wm = wave >> 1, wn = wave & 1;
    const int L = blockIdx.x, xcd = L & 7, ii = L >> 3;
    const long row0 = (long)(xcd * 4 + (ii >> 3)) * 128;
    const long col0 = (long)(ii & 7) * 128;
    floatx4 acc[4][4] = {};
    gemm_loop_db(A + row0 * DIMM, Bt + col0 * DIMM, DIMM, As, Bs, acc);
    #pragma unroll
    for (int mt = 0; mt < 4; ++mt) {
        #pragma unroll
        for (int nt = 0; nt < 4; ++nt) {
            long rr = row0 + wm * 64 + mt * 16 + quad * 4;
            int ccol = (int)col0 + wn * 64 + nt * 16 + l16;
            int d = ccol & 63;
            #pragma unroll
            for (int i = 0; i < 4; ++i) {
                long r = rr + i; int s = (int)(r & 255);
                float c_ = cqT[s * 64 + d], s_ = sqT[s * 64 + d];
                float q = acc[mt][nt][i];
                float pn = __shfl_xor(q, 1);
                float outv = (d & 1) ? (q * c_ + pn * s_) : (q * c_ - pn * s_);
                Qout[r * DIMM + ccol] = (bf16)outv;
            }
        }
    }
}

// -------- K GEMM with fused table-based bias + rotary epilogue --------
// XCD-swizzled 1-D grid (2176 = 8 xcd * 34 row-panels * 8 col-blocks):
// condb A-panel (256KB) staged once into the XCD's L2, then 7 L2 hits.
__global__ __launch_bounds__(256) void gemm_k_kernel(
        const bf16* __restrict__ A, const bf16* __restrict__ Btk,
        bf16* __restrict__ Kout, const float* __restrict__ ckT,
        const float* __restrict__ skT, const float* __restrict__ biasK) {
    __shared__ bf16 As[2 * TILE_ELEMS];
    __shared__ bf16 Bs[2 * TILE_ELEMS];
    const int tid  = threadIdx.x;
    const int wave = tid >> 6, lane = tid & 63;
    const int quad = lane >> 4, l16 = lane & 15;
    const int wm = wave >> 1, wn = wave & 1;
    const int L = blockIdx.x, xcd = L & 7, ii = L >> 3;
    const long row0 = (long)(xcd * 34 + (ii >> 3)) * 128;
    const long col0 = (long)(ii & 7) * 128;
    floatx4 acc[4][4] = {};
    gemm_loop_db(A + row0 * DIMM, Btk + col0 * DIMM, DIMM, As, Bs, acc);
    const int bidx = (int)(row0 / KV_PAD);
    #pragma unroll
    for (int mt = 0; mt < 4; ++mt) {
        #pragma unroll
        for (int nt = 0; nt < 4; ++nt) {
            long rr = row0 + wm * 64 + mt * 16 + quad * 4;
            int ccol = (int)col0 + wn * 64 + nt * 16 + l16;
            int h = ccol >> 6, d = ccol & 63;
            int jbase = (int)(rr - (long)bidx * KV_PAD);
            #pragma unroll
            for (int i = 0; i < 4; ++i) {
                int j = jbase + i;
                float kb = acc[mt][nt][i];
                float c_ = 1.f, s_ = 0.f;
                if (j < MS_TOK) {
                    kb += biasK[((j >> 8) << 4) + h];
                    c_ = ckT[j * 64 + d]; s_ = skT[j * 64 + d];
                }
                float pn = __shfl_xor(kb, 1);
                float outv = (d & 1) ? (kb * c_ + pn * s_) : (kb * c_ - pn * s_);
                Kout[(rr + i) * DIMM + ccol] = (bf16)outv;
            }
        }
    }
}

// -------- V^T GEMM: VT[(b*1024+f), t]; output columns are tokens --------
// XCD-swizzled: each XCD owns 34 condb token-panels; the 8 feature-blocks of a
// panel run consecutively on it -> condb B-panel L2-hits (Wvt is L2-resident).
__global__ __launch_bounds__(256) void gemm_vt_kernel(
        const bf16* __restrict__ Wvt, const bf16* __restrict__ condb,
        bf16* __restrict__ VT) {
    __shared__ bf16 As[2 * TILE_ELEMS];
    __shared__ bf16 Bs[2 * TILE_ELEMS];
    const int tid  = threadIdx.x;
    const int wave = tid >> 6, lane = tid & 63;
    const int quad = lane >> 4, l16 = lane & 15;
    const int wm = wave >> 1, wn = wave & 1;
    const int L = blockIdx.x, xcd = L & 7, ii = L >> 3;
    const int pan = xcd * 34 + (ii >> 3);        // 0..271: b*17 + token-block
    const int b  = pan / KV_BLKS, tb = pan % KV_BLKS;
    const long row0 = (long)(ii & 7) * 128;      // feature
    const long col0 = (long)tb * 128;            // token within batch
    const bf16* Bt = condb + (size_t)b * KV_PAD * DIMM;
    floatx4 acc[4][4] = {};
    gemm_loop_db(Wvt + row0 * DIMM, Bt + col0 * DIMM, DIMM, As, Bs, acc);
    #pragma unroll
    for (int mt = 0; mt < 4; ++mt) {
        #pragma unroll
        for (int nt = 0; nt < 4; ++nt) {
            long f0 = row0 + wm * 64 + mt * 16 + quad * 4;
            long t0 = col0 + wn * 64 + nt * 16 + l16;
            #pragma unroll
            for (int i = 0; i < 4; ++i)
                VT[((size_t)b * DIMM + f0 + i) * KV_PAD + t0] = (bf16)acc[mt][nt][i];
        }
    }
}

// ---------------- flash attention v4: register-prefetched staging ----------------
// XCD-swizzled: the 4 q-tiles of one (b,h) run consecutively on one XCD,
// sharing its K/V panels (544KB) through L2.
__global__ __launch_bounds__(256, 3) void attn_kernel(
        const bf16* __restrict__ Qb, const bf16* __restrict__ Kb,
        const bf16* __restrict__ VT, bf16* __restrict__ Ob) {
    const int L = blockIdx.x, xcd = L & 7, ii = L >> 3;
    const int bh = xcd * 32 + (ii >> 2), qt = ii & 3;
    const int b = bh >> 4, h = bh & 15;
    const int tid = threadIdx.x, wave = tid >> 6, lane = tid & 63;
    const int quad = lane >> 4, l16 = lane & 15;
    __shared__ bf16 Ks[128 * 72];
    __shared__ bf16 Vt[64 * 144];
    __shared__ bf16 Ps[4][16 * 72];

    const int qrow0 = b * SEQ + qt * 64 + wave * 16;
    const bf16* qp = Qb + (size_t)(qrow0 + l16) * DIMM + h * 64 + quad * 8;
    bf16x8 qf0 = *(const bf16x8*)(qp);
    bf16x8 qf1 = *(const bf16x8*)(qp + 32);

    floatx4 oacc[4] = {};
    floatx4 lacc = {};
    bf16x8 ones;
    #pragma unroll
    for (int t = 0; t < 8; ++t) ones[t] = (bf16)1.0f;

    const size_t kbase = ((size_t)b * KV_PAD) * DIMM + h * 64;
    const size_t vbase = ((size_t)(bh * 64)) * KV_PAD;

    const int kchunk = tid & 1;
    const int gl = tid >> 1;
    const int g  = ((gl & 31) << 2) | (gl >> 5);
    const int gg = g & 63;
    const int dstrow = (g >> 6) * 64 + ((gg & 3) << 4) + (gg >> 2);
    const int vd = tid >> 2, vseg = tid & 3;

    bf16x8 kr[4], vr[4];
    // prefetch tile 0
    {
        int jr = g; if (jr > KV_LEN - 1) jr = KV_LEN - 1;
        const bf16* gp = Kb + kbase + (size_t)jr * DIMM + kchunk * 32;
        kr[0] = *(const bf16x8*)(gp);      kr[1] = *(const bf16x8*)(gp + 8);
        kr[2] = *(const bf16x8*)(gp + 16); kr[3] = *(const bf16x8*)(gp + 24);
        const bf16* vp = VT + vbase + (size_t)vd * KV_PAD + vseg * 32;
        vr[0] = *(const bf16x8*)(vp);      vr[1] = *(const bf16x8*)(vp + 8);
        vr[2] = *(const bf16x8*)(vp + 16); vr[3] = *(const bf16x8*)(vp + 24);
    }

    for (int j0 = 0; j0 < KV_LEN; j0 += 128) {
        __syncthreads();           // previous iteration's LDS readers done
        {
            bf16* dp = Ks + dstrow * 72 + kchunk * 32;
            *(bf16x8*)(dp)      = kr[0]; *(bf16x8*)(dp + 8)  = kr[1];
            *(bf16x8*)(dp + 16) = kr[2]; *(bf16x8*)(dp + 24) = kr[3];
            bf16* dv = Vt + vd * 144 + vseg * 32;
            *(bf16x8*)(dv)      = vr[0]; *(bf16x8*)(dv + 8)  = vr[1];
            *(bf16x8*)(dv + 16) = vr[2]; *(bf16x8*)(dv + 24) = vr[3];
        }
        __syncthreads();           // LDS tile ready
        if (j0 + 128 < KV_LEN) {   // prefetch next tile; completes during compute
            int jr = j0 + 128 + g; if (jr > KV_LEN - 1) jr = KV_LEN - 1;
            const bf16* gp = Kb + kbase + (size_t)jr * DIMM + kchunk * 32;
            kr[0] = *(const bf16x8*)(gp);      kr[1] = *(const bf16x8*)(gp + 8);
            kr[2] = *(const bf16x8*)(gp + 16); kr[3] = *(const bf16x8*)(gp + 24);
            const bf16* vp = VT + vbase + (size_t)vd * KV_PAD + j0 + 128 + vseg * 32;
            vr[0] = *(const bf16x8*)(vp);      vr[1] = *(const bf16x8*)(vp + 8);
            vr[2] = *(const bf16x8*)(vp + 16); vr[3] = *(const bf16x8*)(vp + 24);
        }
        #pragma unroll
        for (int c = 0; c < 2; ++c) {
            floatx4 s[4] = {};
            #pragma unroll
            for (int jt = 0; jt < 4; ++jt) {
                const bf16* kp = Ks + (c * 64 + jt * 16 + l16) * 72 + quad * 8;
                bf16x8 kb0 = *(const bf16x8*)(kp);
                bf16x8 kb1 = *(const bf16x8*)(kp + 32);
                s[jt] = __builtin_amdgcn_mfma_f32_16x16x32_bf16(qf0, kb0, s[jt], 0, 0, 0);
                s[jt] = __builtin_amdgcn_mfma_f32_16x16x32_bf16(qf1, kb1, s[jt], 0, 0, 0);
            }
            const int colbase = j0 + c * 64 + 4 * l16;
            #pragma unroll
            for (int r = 0; r < 4; ++r) {
                bf16x4 pk;
                #pragma unroll
                for (int jt = 0; jt < 4; ++jt) {
                    bool ok = (colbase + jt) < KV_LEN;
                    float p = ok ? __expf(s[jt][r] * ATT_SCALE) : 0.f;
                    pk[jt] = (bf16)p;
                }
                *(bf16x4*)(&Ps[wave][(quad * 4 + r) * 72 + l16 * 4]) = pk;
            }
            #pragma unroll
            for (int kf = 0; kf < 2; ++kf) {
                bf16x8 pa = *(const bf16x8*)(&Ps[wave][l16 * 72 + kf * 32 + quad * 8]);
                lacc = __builtin_amdgcn_mfma_f32_16x16x32_bf16(pa, ones, lacc, 0, 0, 0);
                #pragma unroll
                for (int dt = 0; dt < 4; ++dt) {
                    bf16x8 vb = *(const bf16x8*)(Vt + (dt * 16 + l16) * 144 + c * 64 + kf * 32 + quad * 8);
                    oacc[dt] = __builtin_amdgcn_mfma_f32_16x16x32_bf16(pa, vb, oacc[dt], 0, 0, 0);
                }
            }
        }
    }
    #pragma unroll
    for (int r = 0; r < 4; ++r) {
        float inv = 1.f / lacc[r];
        size_t orow = (size_t)(qrow0 + quad * 4 + r) * DIMM + h * 64;
        #pragma unroll
        for (int dt = 0; dt < 4; ++dt)
            Ob[orow + dt * 16 + l16] = (bf16)(oacc[dt][r] * inv);
    }
}

extern "C" void kernel_launch(void* const* d_in, const int* in_sizes, int n_in,
                              void* d_out, int out_size, void* d_ws, size_t ws_size,
                              hipStream_t stream) {
    const float* x     = (const float*)d_in[0];
    const float* cond  = (const float*)d_in[1];
    const float* freqs = (const float*)d_in[2];
    const float* Wq    = (const float*)d_in[3];
    const float* Wk    = (const float*)d_in[4];
    const float* Wv    = (const float*)d_in[5];
    const float* rel   = (const float*)d_in[6];
    const float* Wo    = (const float*)d_in[7];
    const float* bo    = (const float*)d_in[8];
    const int* mem_idxs = (const int*)d_in[9];
    const int* cur      = (const int*)d_in[10];
    float* out = (float*)d_out;

    const int B   = 16;
    const int Mq  = B * SEQ;                 // 4096
    const int Mkv_pad = B * KV_PAD;          // 34816

    char* ws = (char*)d_ws;
    size_t off = 0;
    auto alloc = [&](size_t bytes) { void* pp = ws + off; off = (off + bytes + 255) & ~(size_t)255; return pp; };
    bf16* xb    = (bf16*)alloc((size_t)Mq * DIMM * 2);
    bf16* condb = (bf16*)alloc((size_t)Mkv_pad * DIMM * 2);
    bf16* Wqt   = (bf16*)alloc((size_t)DIMM * DIMM * 2);
    bf16* Wkt   = (bf16*)alloc((size_t)DIMM * DIMM * 2);
    bf16* Wvt   = (bf16*)alloc((size_t)DIMM * DIMM * 2);
    bf16* Wot   = (bf16*)alloc((size_t)DIMM * DIMM * 2);
    bf16* Qb    = (bf16*)alloc((size_t)Mq * DIMM * 2);
    bf16* Kb    = (bf16*)alloc((size_t)Mkv_pad * DIMM * 2);
    bf16* VTb   = (bf16*)alloc((size_t)B * DIMM * KV_PAD * 2);
    bf16* Ab    = (bf16*)alloc((size_t)Mq * DIMM * 2);
    float* ckT  = (float*)alloc((size_t)MS_TOK * 64 * 4);
    float* skT  = (float*)alloc((size_t)MS_TOK * 64 * 4);
    float* cqT  = (float*)alloc((size_t)SEQ * 64 * 4);
    float* sqT  = (float*)alloc((size_t)SEQ * 64 * 4);
    float* biasK = (float*)alloc(128 * 4);

    long xtot = (long)Mq * DIMM;
    convert_kernel<<<(int)((xtot / 4 + 255) / 256), 256, 0, stream>>>(x, xb, xtot);
    long ctot = (long)Mkv_pad * DIMM;
    convert_cond_kernel<<<(int)((ctot / 4 + 255) / 256), 256, 0, stream>>>(cond, condb, ctot);
    dim3 tg(32, 32);
    transpose_bf16_kernel<<<tg, 256, 0, stream>>>(Wq, Wqt, DIMM);
    transpose_bf16_kernel<<<tg, 256, 0, stream>>>(Wk, Wkt, DIMM);
    transpose_bf16_kernel<<<tg, 256, 0, stream>>>(Wv, Wvt, DIMM);
    transpose_bf16_kernel<<<tg, 256, 0, stream>>>(Wo, Wot, DIMM);

    int ttot = MS_TOK * 64 + SEQ * 64 + 128;
    rot_tables_kernel<<<(ttot + 255) / 256, 256, 0, stream>>>(
        freqs, rel, mem_idxs, cur, ckT, skT, cqT, sqT, biasK);

    gemm_q_rot_kernel<<<256, 256, 0, stream>>>(xb, Wqt, Qb, cqT, sqT);
    gemm_k_kernel<<<2176, 256, 0, stream>>>(condb, Wkt, Kb, ckT, skT, biasK);
    gemm_vt_kernel<<<2176, 256, 0, stream>>>(Wvt, condb, VTb);

    attn_kernel<<<1024, 256, 0, stream>>>(Qb, Kb, VTb, Ab);

    gemm_o_kernel<<<256, 256, 0, stream>>>(Ab, Wot, out, bo, DIMM);
}